// Round 12
// baseline (232.140 us; speedup 1.0000x reference)
//
#include <hip/hip_runtime.h>
#include <cmath>
#include <cstring>
#include <cstdlib>
#include <algorithm>

// ---------------- problem constants ----------------
#define BATCH 32

static constexpr float SC1f = 0.03872983346207417f;   // 1/sqrt(2*30*1*10^4/30^2)
static constexpr float SC2f = 0.06324555320336759f;   // 1/sqrt(250)

// table layout (float offsets inside the table blob)
#define OFF_D1W 0
#define N_D1W (10*60*19)
#define OFF_C1  (OFF_D1W + N_D1W)      // [10][20][19][19]
#define N_C1  (10*20*19*19)
#define OFF_D2W (OFF_C1 + N_C1)        // [5][20][9][9]
#define N_D2W (5*20*81)
#define OFF_DH2 (OFF_D2W + N_D2W)      // [5][9][9]
#define N_DH2 (5*81)
#define OFF_DI2 (OFF_DH2 + N_DH2)      // [5][10][9][9]
#define N_DI2 (5*10*81)
#define OFF_WO  (OFF_DI2 + N_DI2)      // [10]
#define TBL_N   (OFF_WO + 10)

#define Z2HALF ((size_t)165*32*200)
#define NPART 5

__constant__ int d_RNI[9] = {9,16,21,24,25,24,21,16,9};
__constant__ int d_RS [9] = {0,9,25,46,70,95,119,140,156};

__device__ __forceinline__ float2 cmulf(float2 a, float2 b){
  return make_float2(a.x*b.x - a.y*b.y, a.x*b.y + a.y*b.x);
}

// ---------------- K_front v2 ----------------
// kf1 one-thread-per-(o,mi); incremental wrapped DFT indices everywhere.
//  blocks 0..7    : kf1  (1900 threads)
//  blocks 8..86   : kf2  (20000 threads)
//  blocks 87..229 : xf1  (36480 threads)
__global__ void k_front(const float* __restrict__ k1, const float* __restrict__ k2,
                        const float* __restrict__ x,
                        float2* __restrict__ kf1, float2* __restrict__ kf2,
                        float2* __restrict__ xf1){
  __shared__ float c60[60], s60[60], c20[20], s20[20];
  int t = threadIdx.x;
  if (t < 60){ float a = 6.283185307179586f * t / 60.f; c60[t]=cosf(a); s60[t]=sinf(a); }
  if (t < 20){ float a = 6.283185307179586f * t / 20.f; c20[t]=cosf(a); s20[t]=sinf(a); }
  __syncthreads();
  int bid = blockIdx.x;
  if (bid < 8){
    int gid = bid*256 + t;
    if (gid >= 1900) return;
    int o = gid/19, mi = gid%19;
    int m = mi-9;
    int step = m + 60; if (step >= 60) step -= 60;
    int idx = 0;
    float ax=0.f, ay=0.f;
    const float* kr = k1 + o*60;
    for (int j=0;j<60;j++){
      float kv = kr[j];
      ax += kv*c60[idx]; ay -= kv*s60[idx];
      idx += step; if (idx >= 60) idx -= 60;
    }
    kf1[mi*100+o] = make_float2(ax*SC1f, ay*SC1f);
  } else if (bid < 87){
    int gid = (bid-8)*256 + t;
    if (gid >= 20000) return;
    int i = gid/200, o = gid%200;
    float kv[20];
    #pragma unroll
    for (int p=0;p<20;p++) kv[p] = k2[(i*200+o)*20+p];
    #pragma unroll
    for (int mi=0; mi<9; mi++){
      int m = mi-4;
      int step = m + 20; if (step >= 20) step -= 20;
      int idx = 0;
      float ax=0.f, ay=0.f;
      #pragma unroll
      for (int p=0;p<20;p++){
        ax += kv[p]*c20[idx]; ay -= kv[p]*s20[idx];
        idx += step; if (idx >= 20) idx -= 20;
      }
      kf2[(size_t)(mi*100+i)*200+o] = make_float2(ax*SC2f, ay*SC2f);
    }
  } else {
    int gid = (bid-87)*256 + t;
    if (gid >= 19*32*60) return;
    int z = gid%60, b = (gid/60)%32, mi = gid/1920;
    int m = mi-9;
    int step = m + 60; if (step >= 60) step -= 60;
    int idx = 0;
    const float* xr = x + (b*60 + z)*60;
    float ax=0.f, ay=0.f;
    for (int j=0;j<60;j++){
      float xv = xr[j];
      ax += xv*c60[idx]; ay -= xv*s60[idx];
      idx += step; if (idx >= 60) idx -= 60;
    }
    xf1[(mi*32+b)*60+z] = make_float2(ax, ay);
  }
}

// ---------------- K3: fused xh1 + Q + P. Block per (b,z) ----------------
// k_xhat1 fused: the 190 xh1 values for this b recomputed per block (20x
// redundant across z, trivial; xf1 L2-resident) into 1.5KB LDS.
__launch_bounds__(256)
__global__ void k_QP(const float* __restrict__ tbl, const float2* __restrict__ xf1,
                     float2* __restrict__ P){
  __shared__ float2 xh1s[190];      // [l*19+mi]
  __shared__ float2 Qs[361];
  __shared__ float c20[20], s20[20];
  int t = threadIdx.x;
  if (t < 20){ float a = 6.283185307179586f * t / 20.f; c20[t]=cosf(a); s20[t]=sinf(a); }
  int bz = blockIdx.x;              // b*20+z
  int z = bz % 20, b = bz / 20;
  // stage 0: xh1[l][mi] for this b
  if (t < 190){
    int l = t/19, mi = t%19;
    const float* d1w = tbl + OFF_D1W;
    const float2* xr = xf1 + (size_t)(mi*32+b)*60;
    float ax=0.f, ay=0.f;
    for (int zz=0; zz<60; zz++){
      float w = d1w[(l*60+zz)*19+mi];
      float2 v = xr[zz];
      ax += w*v.x; ay += w*v.y;
    }
    xh1s[t] = make_float2(ax, ay);
  }
  __syncthreads();
  const float* C1 = tbl + OFF_C1;
  for (int e=t; e<361; e+=256){
    int mi = e/19;
    float ax=0.f, ay=0.f;
    #pragma unroll
    for (int l=0;l<10;l++){
      float c = C1[(l*20+z)*361 + e];
      float2 xv = xh1s[l*19+mi];            // LDS broadcast across the 19 ni
      ax += c*xv.x; ay += c*xv.y;
    }
    Qs[e] = make_float2(ax, ay);
  }
  __syncthreads();
  if (t < 200){
    int j1 = t%20, n = t/20;
    float px=0.f, py=0.f;
    int idx = (11*j1)%20;      // (-9*j1) mod 20
    int step = j1;
    #pragma unroll
    for (int mi=0;mi<19;mi++){
      float c=c20[idx], s=s20[idx];
      float2 v = Qs[mi*19 + n+9];           // same addr for 20 threads: broadcast
      px += c*v.x - s*v.y;
      py += c*v.y + s*v.x;
      idx += step; if (idx >= 20) idx -= 20;
    }
    P[(size_t)bz*200 + t] = make_float2(px, py);
  }
}

// ---------------- K4: fused layer-1 synth + ReLU + layer-2 analysis + xh2 ----------------
// v8: xh2 layout TRANSPOSED to [widx][lmk]. The 40.5MB-vs-10.4-logical write
// amplification was TEMPORAL: one 64B line of the old [lmk][widx] layout was
// written by 8 blocks finishing at different times (R8 falsified the spatial
// XCD model: spreading writers made it worse). Transposed, each block writes
// its 405 values as one contiguous 3240B run — every line written once, by one
// block. k_Xp's ki-loop becomes stride-1.
// FALSIFICATION: if k_l1 stays ~55us with WRITE ~11MB, write path was fully
// absorbed -> k_l1 is pure VALU/LDS-latency bound; pivot or stop.
__launch_bounds__(256,2)
__global__ void k_l1(const float* __restrict__ tbl,
                     const float2* __restrict__ P, const float2* __restrict__ kf1,
                     const float* __restrict__ b1, float2* __restrict__ xh2){
  int o = blockIdx.x % 100, b = blockIdx.x / 100;

  __shared__ __align__(16) float2 tw9[10][10];
  __shared__ __align__(16) float2 tw5[5][10];
  __shared__ __align__(16) float  reA[4][20][12];
  __shared__ __align__(16) float  roA[4][20][12];
  __shared__ __align__(16) float2 AeA[4][5][10];
  __shared__ __align__(16) float2 AoA[4][5][10];
  __shared__ __align__(16) float2 xs[20][46];   // slab tile, padded rows

  int t = threadIdx.x, w = t>>6, lane = t&63;
  const float a1 = 0.3141592653589793f; // 2*pi/20

  for (int e=t; e<140; e+=256){
    if (e < 90){
      int j2=e/9, n=e%9+1;
      int idx=(n*j2)%20;
      float ang = a1*idx;
      tw9[j2][n-1] = make_float2(2.f*cosf(ang), -2.f*sinf(ang));
    } else {
      int q=e-90; int k=q/10, j=q%10;
      int idx=(k*j)%20;
      float ang = a1*idx;
      tw5[k][j] = make_float2(cosf(ang), -sinf(ang));
    }
  }

  float2 kc[10];
  #pragma unroll
  for (int n=0;n<10;n++){ float2 k = kf1[(n+9)*100+o]; kc[n]=make_float2(k.x,-k.y); }
  float b1v = b1[o];

  int j1 = lane%20, jg = lane/20;

  __syncthreads();

  float2 twB[10];
  {
    const float2* tb = &tw5[lane%5][0];
    #pragma unroll
    for (int j=0;j<10;j++) twB[j] = tb[j];
  }

  const float2* pz0 = P + (size_t)(b*20)*200;

  for (int zz=0; zz<5; zz++){
    int z = w*5 + zz;
    const float2* pz = pz0 + (size_t)z*200;
    float2 V[10];
    #pragma unroll
    for (int n=0;n<10;n++){
      float2 p = pz[n*20 + j1];
      V[n] = make_float2(p.x*kc[n].x - p.y*kc[n].y, p.x*kc[n].y + p.y*kc[n].x);
    }

    #pragma unroll
    for (int tt=0; tt<4; tt++){
      int j2 = jg + 3*tt;
      if (jg < 3 && j2 < 10){
        const float4* tq = (const float4*)&tw9[j2][0];
        float4 t0=tq[0], t1=tq[1], t2=tq[2], t3=tq[3];
        float2 t4=((const float2*)tq)[8];
        float o0=0.f, o1=0.f, e0=0.f, e1=0.f;
        o0 += V[1].x*t0.x + V[1].y*t0.y;
        e0 += V[2].x*t0.z + V[2].y*t0.w;
        o1 += V[3].x*t1.x + V[3].y*t1.y;
        e1 += V[4].x*t1.z + V[4].y*t1.w;
        o0 += V[5].x*t2.x + V[5].y*t2.y;
        e0 += V[6].x*t2.z + V[6].y*t2.w;
        o1 += V[7].x*t3.x + V[7].y*t3.y;
        e1 += V[8].x*t3.z + V[8].y*t3.w;
        o0 += V[9].x*t4.x + V[9].y*t4.y;
        float base = b1v + V[0].x;
        float e_ = e0+e1, o_ = o0+o1;
        float r0 = fmaxf(base + e_ + o_, 0.f);
        float r1 = fmaxf(base + e_ - o_, 0.f);
        reA[w][j1][j2] = r0 + r1;
        roA[w][j1][j2] = r0 - r1;
      }
    }

    if (lane < 50){
      int N = lane%5, j1p = lane/5;
      const float* rb = (N&1) ? &roA[w][0][0] : &reA[w][0][0];
      const float4* q0 = (const float4*)(rb + j1p*12);
      const float4* q1 = (const float4*)(rb + (j1p+10)*12);
      float4 x0=q0[0], x1=q0[1]; float2 x2=((const float2*)q0)[4];
      float4 y0=q1[0], y1=q1[1]; float2 y2=((const float2*)q1)[4];
      float r0v[10] = {x0.x,x0.y,x0.z,x0.w,x1.x,x1.y,x1.z,x1.w,x2.x,x2.y};
      float r1v[10] = {y0.x,y0.y,y0.z,y0.w,y1.x,y1.y,y1.z,y1.w,y2.x,y2.y};
      float ax0=0.f, ay0=0.f, ax1=0.f, ay1=0.f;
      #pragma unroll
      for (int j=0;j<10;j++){
        ax0 += r0v[j]*twB[j].x; ay0 += r0v[j]*twB[j].y;
        ax1 += r1v[j]*twB[j].x; ay1 += r1v[j]*twB[j].y;
      }
      AeA[w][N][j1p] = make_float2(ax0+ax1, ay0+ay1);
      AoA[w][N][j1p] = make_float2(ax0-ax1, ay0-ay1);
    }

    if (lane < 45){
      int M = lane/9, Ni = lane%9, Nv = Ni-4;
      int sidx = (Nv>=0)? Nv : -Nv;
      float ysgn = (Nv>=0)? 1.f : -1.f;
      const float4* Ab4 = (const float4*)((M&1) ? &AoA[w][sidx][0] : &AeA[w][sidx][0]);
      const float4* tC4 = (const float4*)&tw5[M][0];
      float ox0=0.f, ox1=0.f, oy0=0.f, oy1=0.f;
      #pragma unroll
      for (int q=0;q<5;q++){
        float4 Aq = Ab4[q];
        float4 Tq = tC4[q];
        float Ay0 = ysgn*Aq.y, Ay1 = ysgn*Aq.w;
        ox0 += Tq.x*Aq.x - Tq.y*Ay0;
        oy0 += Tq.x*Ay0 + Tq.y*Aq.x;
        ox1 += Tq.z*Aq.z - Tq.w*Ay1;
        oy1 += Tq.z*Ay1 + Tq.w*Aq.z;
      }
      xs[z][lane] = make_float2(ox0+ox1, oy0+oy1);   // LDS, not global
    }
  }

  // ---- fused xh2 accumulation: TRANSPOSED write xh2[b*100+o][lmk] ----
  __syncthreads();
  const float* d2w = tbl + OFF_D2W;
  float2* xrow = xh2 + (size_t)(b*100 + o)*405;
  for (int e=t; e<405; e+=256){
    int l = e/81, mk = e%81;
    int mi = mk/9, ki = mk%9;
    int sidx; float sgn;
    if (mi>=4){ sidx=(mi-4)*9+ki; sgn=1.f; }
    else      { sidx=(4-mi)*9+(8-ki); sgn=-1.f; }
    float ax=0.f, ay=0.f;
    #pragma unroll 4
    for (int z=0;z<20;z++){
      float wv = d2w[(l*20+z)*81+mk];
      float2 v = xs[z][sidx];
      ax += wv*v.x; ay += wv*sgn*v.y;
    }
    xrow[e] = make_float2(ax, ay);   // contiguous 3240B per block
  }
}

// ---------------- K6: A rows for GEMM (reads transposed xh2, stride-1 ki loop) ----------------
__global__ void k_Xp(const float* __restrict__ tbl, const float2* __restrict__ xh2,
                     float2* __restrict__ Am){
  int ni = blockIdx.y;
  int R = d_RNI[ni];
  int gid = blockIdx.x*256 + threadIdx.x;
  if (gid >= R*3200) return;
  int r = gid/3200, rem = gid%3200, b = rem/100, i = rem%100;
  int a = ni-4; if (a<0) a=-a;
  int l=a, rr=r;
  while (rr >= 2*l+1){ rr -= 2*l+1; l++; }
  int m = rr - l;
  const float* dh2 = tbl + OFF_DH2;
  const float2* xrow = xh2 + (size_t)(b*100 + i)*405 + l*81 + (m+4)*9 + (4-l);
  const float* wrow = dh2 + l*81 + ni*9 + (4-l);
  float ax=0.f, ay=0.f;
  for (int ki=0; ki<2*l+1; ki++){
    float w = wrow[ki];
    float2 v = xrow[ki];              // stride-1 (was stride 25.6KB)
    ax += w*v.x; ay += w*v.y;
  }
  Am[(size_t)((d_RS[ni]+r)*32 + b)*100 + i] = make_float2(ax,ay);
}

// ---------------- K7: complex GEMM v3 (measured best) ----------------
// col-tiles of 40 (5x40=200 exact); K-split x5 (K=20/block, single stage +
// single barrier); 2125 active blocks. R8 showed block-count beats traffic.
__launch_bounds__(256)
__global__ void k_gemm(const float2* __restrict__ Am, const float2* __restrict__ kf2,
                       float2* __restrict__ z2p){
  int zi = blockIdx.z;            // 0..44 = ni*5 + ks
  int ni = zi/5, ks = zi%5;
  int rows = d_RNI[ni]*32;
  int r0 = blockIdx.x*64;
  if (r0 >= rows) return;
  int c0 = blockIdx.y*40;
  const float2* Ab = Am + (size_t)d_RS[ni]*32*100;
  const float2* Bb = kf2 + (size_t)ni*20000 + (size_t)ks*20*200;
  float2* Cb = z2p + (size_t)ks*Z2HALF + (size_t)d_RS[ni]*32*200;
  __shared__ float2 Asx[64*21];   // [m][k], pad 21
  __shared__ float2 Bsx[20*40];   // [k][n]
  int t = threadIdx.x;
  #pragma unroll
  for (int e=t; e<1280; e+=256){
    int m=e/20, k=e%20;
    float2 v=make_float2(0.f,0.f);
    if (r0+m<rows) v=Ab[(size_t)(r0+m)*100 + ks*20 + k];
    Asx[m*21+k]=v;
  }
  for (int e=t; e<800; e+=256){
    int k=e/40, n=e%40;
    float2 v=Bb[(size_t)k*200 + c0+n];
    v.y=-v.y;
    Bsx[k*40+n]=v;
  }
  __syncthreads();
  int tx = t%8, ty = t/8;   // cols c0+tx*5.., rows r0+ty*2..
  float2 acc[2][5];
  #pragma unroll
  for (int i=0;i<2;i++)
    #pragma unroll
    for (int j=0;j<5;j++) acc[i][j]=make_float2(0.f,0.f);
  #pragma unroll 4
  for (int k=0;k<20;k++){
    float2 a0=Asx[(ty*2)*21+k], a1=Asx[(ty*2+1)*21+k];
    float2 bv[5];
    #pragma unroll
    for (int j=0;j<5;j++) bv[j]=Bsx[k*40+tx*5+j];
    #pragma unroll
    for (int j=0;j<5;j++){
      acc[0][j].x += a0.x*bv[j].x - a0.y*bv[j].y;
      acc[0][j].y += a0.x*bv[j].y + a0.y*bv[j].x;
      acc[1][j].x += a1.x*bv[j].x - a1.y*bv[j].y;
      acc[1][j].y += a1.x*bv[j].y + a1.y*bv[j].x;
    }
  }
  #pragma unroll
  for (int i=0;i<2;i++){
    int row=r0+ty*2+i;
    if (row<rows){
      #pragma unroll
      for (int j=0;j<5;j++) Cb[(size_t)row*200 + c0+tx*5+j]=acc[i][j];
    }
  }
}

// ---------------- K8: fused layer-2 synthesis + ReLU + quadrature pooling ----------------
// Block = (b, o-group-of-8), 512 threads, 8 waves; wave w owns o = og*8+w and
// all 10 z. Load sums the 5 partials reading 8 consecutive o per slot = one
// aligned 64B line, each line touched once across the grid.
__launch_bounds__(512)
__global__ void k_l2(const float* __restrict__ tbl, const float2* __restrict__ z2p,
                     const float* __restrict__ b2, float* __restrict__ fv){
  int b = blockIdx.x / 25, og = blockIdx.x % 25;
  __shared__ float2 zlh8[8][225];  // [o_l][slot]
  __shared__ float  c10s[10], s10s[10];
  __shared__ float2 Gw[8][45];
  __shared__ float2 Fw[8][50];
  int t = threadIdx.x, w = t>>6, lane = t&63;
  if (t < 10){ float a = 0.6283185307179586f * t; c10s[t]=cosf(a); s10s[t]=sinf(a); }
  int o0 = og*8;
  for (int e=t;e<1800;e+=512){
    int slot=e>>3, o_l=e&7;
    int l=slot/45, rm=slot%45, m=rm/9, nii=rm%9;
    int n=nii-4, an = n<0?-n:n;
    float2 v=make_float2(0.f,0.f);
    if (l >= m && l >= an){
      size_t idx = (size_t)((d_RS[nii] + (l*l - an*an + m + l))*32+b)*200 + o0 + o_l;
      #pragma unroll
      for (int p=0;p<NPART;p++){
        float2 vp = z2p[idx + (size_t)p*Z2HALF];
        v.x += vp.x; v.y += vp.y;
      }
    }
    zlh8[o_l][slot]=v;
  }
  __syncthreads();
  const float* di2 = tbl + OFF_DI2;
  const float* wo  = tbl + OFF_WO;
  int o = o0 + w;
  float b2v = b2[o];
  float accv = 0.f;
  for (int z=0; z<10; z++){
    if (lane < 45){
      int m=lane/9, nii=lane%9;
      float gx=0.f, gy=0.f;
      #pragma unroll
      for (int l=0;l<5;l++){
        float wv = di2[(l*10+z)*81 + (m+4)*9 + nii];
        float2 v = zlh8[w][(l*5+m)*9+nii];
        gx += wv*v.x; gy += wv*v.y;
      }
      Gw[w][lane]=make_float2(gx,gy);
    }
    if (lane < 50){
      int m=lane/10, j2=lane%10;
      if (m==0){
        float f0 = Gw[w][4].x;
        #pragma unroll
        for (int n=1;n<=4;n++){
          int idx=(n*j2)%10;
          float2 g=Gw[w][4+n];
          f0 += 2.f*(c10s[idx]*g.x - s10s[idx]*g.y);
        }
        Fw[w][lane]=make_float2(f0, 0.f);
      } else {
        float fx=0.f, fy=0.f;
        #pragma unroll
        for (int nii=0;nii<9;nii++){
          int n=nii-4;
          int idx=((n*j2)%10+10)%10;
          float2 g=Gw[w][m*9+nii];
          fx += c10s[idx]*g.x - s10s[idx]*g.y;
          fy += s10s[idx]*g.x + c10s[idx]*g.y;
        }
        Fw[w][lane]=make_float2(fx,fy);
      }
    }
    float wz = wo[z];
    {
      int j1=lane/10, j2=lane%10;
      float v = b2v + Fw[w][j2].x;
      #pragma unroll
      for (int m=1;m<=4;m++){
        int idx=(m*j1)%10;
        float2 f=Fw[w][m*10+j2];
        v += 2.f*(c10s[idx]*f.x - s10s[idx]*f.y);
      }
      accv += wz*fmaxf(v,0.f);
    }
    if (lane < 36){
      int e=lane+64, j1=e/10, j2=e%10;
      float v = b2v + Fw[w][j2].x;
      #pragma unroll
      for (int m=1;m<=4;m++){
        int idx=(m*j1)%10;
        float2 f=Fw[w][m*10+j2];
        v += 2.f*(c10s[idx]*f.x - s10s[idx]*f.y);
      }
      accv += wz*fmaxf(v,0.f);
    }
  }
  #pragma unroll
  for (int s=32;s>0;s>>=1) accv += __shfl_down(accv, s);
  if (lane==0) fv[b*200+o]=accv;
}

// ---------------- K9: out[b][c] = bl[c] + sum_o W[c][o] fv[b][o]; one block per b ----------------
__global__ void k_out(const float* __restrict__ fv, const float* __restrict__ W,
                      const float* __restrict__ bl, float* __restrict__ out){
  int b = blockIdx.x, lane = threadIdx.x;
  float acc[10];
  #pragma unroll
  for (int c=0;c<10;c++) acc[c]=0.f;
  #pragma unroll
  for (int k=0;k<4;k++){
    int o = lane + 64*k;
    if (o < 200){
      float fvx = fv[b*200+o];
      #pragma unroll
      for (int c=0;c<10;c++) acc[c] += W[c*200+o]*fvx;
    }
  }
  #pragma unroll
  for (int c=0;c<10;c++){
    float a = acc[c];
    #pragma unroll
    for (int s=32;s>0;s>>=1) a += __shfl_down(a, s);
    if (lane==0) out[b*10+c] = a + bl[c];
  }
}

// ======================= host-side constant tables =======================
namespace {

double dfact_[40];
void init_fact(){ dfact_[0]=1.0; for (int i=1;i<40;i++) dfact_[i]=dfact_[i-1]*i; }

double wigd(int l, double beta, int m, int n){
  double cb=std::cos(beta*0.5), sb=std::sin(beta*0.5);
  double pref=std::sqrt(dfact_[l+m]*dfact_[l-m]*dfact_[l+n]*dfact_[l-n]);
  int s0=std::max(0,n-m), s1=std::min(l+n,l-m);
  double acc=0.0;
  for (int s=s0;s<=s1;s++){
    double den=dfact_[l+n-s]*dfact_[s]*dfact_[m-n+s]*dfact_[l-m-s];
    double sg=((m-n+s)&1)?-1.0:1.0;
    acc+=sg/den*std::pow(cb,(double)(2*l+n-m-2*s))*std::pow(sb,(double)(m-n+2*s));
  }
  return pref*acc;
}

void quadw(int b, double* betas, double* w){
  int n=2*b;
  for (int j=0;j<n;j++){
    betas[j]=M_PI*(2*j+1)/(4.0*b);
    double s=0.0;
    for (int k=1;k<2*b;k+=2) s+=std::sin(k*betas[j])/k;
    w[j]=2.0/b*std::sin(betas[j])*s;
  }
}

float* g_tbl_host = nullptr;

void build_tables(){
  init_fact();
  double bin[60], win[60], bl1[20], wl1[20], bo10[10], wo10[10];
  quadw(30,bin,win); quadw(10,bl1,wl1); quadw(5,bo10,wo10);
  float* T = g_tbl_host;
  memset(T, 0, TBL_N*sizeof(float));
  for (int l=0;l<10;l++) for (int z=0;z<60;z++) for (int mi=0;mi<19;mi++){
    int m=mi-9; if (m<-l||m>l) continue;
    T[OFF_D1W+(l*60+z)*19+mi]=(float)(win[z]*wigd(l,bin[z],m,0));
  }
  for (int l=0;l<10;l++) for (int z=0;z<20;z++) for (int mi=0;mi<19;mi++) for (int ni=0;ni<19;ni++){
    int m=mi-9, n=ni-9; if (m<-l||m>l||n<-l||n>l) continue;
    T[OFF_C1+(l*20+z)*361+mi*19+ni]=(float)((2*l+1)*wigd(l,bl1[z],m,n)*wigd(l,M_PI/2,n,0));
  }
  for (int l=0;l<5;l++) for (int z=0;z<20;z++) for (int mi=0;mi<9;mi++) for (int ki=0;ki<9;ki++){
    int m=mi-4, k=ki-4; if (m<-l||m>l||k<-l||k>l) continue;
    T[OFF_D2W+(l*20+z)*81+mi*9+ki]=(float)(wl1[z]*wigd(l,bl1[z],m,k));
  }
  for (int l=0;l<5;l++) for (int ni=0;ni<9;ni++) for (int ki=0;ki<9;ki++){
    int n=ni-4, k=ki-4; if (n<-l||n>l||k<-l||k>l) continue;
    T[OFF_DH2+l*81+ni*9+ki]=(float)wigd(l,M_PI/2,n,k);
  }
  for (int l=0;l<5;l++) for (int z=0;z<10;z++) for (int mi=0;mi<9;mi++) for (int ni=0;ni<9;ni++){
    int m=mi-4, n=ni-4; if (m<-l||m>l||n<-l||n>l) continue;
    T[OFF_DI2+(l*10+z)*81+mi*9+ni]=(float)((2*l+1)*wigd(l,bo10[z],m,n));
  }
  for (int z=0;z<10;z++) T[OFF_WO+z]=(float)wo10[z];
}

struct GInit {
  GInit(){
    if (hipHostMalloc((void**)&g_tbl_host, TBL_N*sizeof(float)) != hipSuccess || !g_tbl_host){
      g_tbl_host = (float*)malloc(TBL_N*sizeof(float));
    }
    build_tables();
  }
};
GInit g_init_;

} // namespace

extern "C" void kernel_launch(void* const* d_in, const int* in_sizes, int n_in,
                              void* d_out, int out_size, void* d_ws, size_t ws_size,
                              hipStream_t stream) {
  const float* x  = (const float*)d_in[0];
  const float* k1 = (const float*)d_in[1];
  const float* b1 = (const float*)d_in[2];
  const float* k2 = (const float*)d_in[3];
  const float* b2 = (const float*)d_in[4];
  const float* W  = (const float*)d_in[5];
  const float* bl = (const float*)d_in[6];
  float* out = (float*)d_out;

  size_t off = 0;
  auto carve = [&](size_t bytes)->void*{
    void* p = (char*)d_ws + off;
    off += (bytes + 255) & ~(size_t)255;
    return p;
  };
  float*  t_tbl = (float*) carve((size_t)TBL_N*4);
  float2* kf1   = (float2*)carve((size_t)19*100*8);
  float2* kf2   = (float2*)carve((size_t)9*100*200*8);
  float2* xf1   = (float2*)carve((size_t)19*32*60*8);
  float2* Pb    = (float2*)carve((size_t)32*20*200*8);
  float2* xh2   = (float2*)carve((size_t)3200*405*8);   // transposed [widx][lmk]
  float2* Am    = (float2*)carve((size_t)165*32*100*8);
  float2* z2p   = (float2*)carve((size_t)NPART*Z2HALF*8); // five K-partials
  float*  fv    = (float*) carve((size_t)6400*4);
  (void)ws_size; (void)in_sizes; (void)n_in; (void)out_size;

  hipMemcpyAsync(t_tbl, g_tbl_host, (size_t)TBL_N*4, hipMemcpyHostToDevice, stream);

  k_front<<<230, 256, 0, stream>>>(k1, k2, x, kf1, kf2, xf1);
  k_QP   <<<640, 256, 0, stream>>>(t_tbl, xf1, Pb);
  k_l1   <<<3200, 256, 0, stream>>>(t_tbl, Pb, kf1, b1, xh2);
  k_Xp   <<<dim3(313, 9), 256, 0, stream>>>(t_tbl, xh2, Am);
  k_gemm <<<dim3(13, 5, 45), 256, 0, stream>>>(Am, kf2, z2p);
  k_l2   <<<800, 512, 0, stream>>>(t_tbl, z2p, b2, fv);
  k_out  <<<32, 64, 0, stream>>>(fv, W, bl, out);
}

// Round 13
// 216.001 us; speedup vs baseline: 1.0747x; 1.0747x over previous
//
#include <hip/hip_runtime.h>
#include <cmath>
#include <cstring>
#include <cstdlib>
#include <algorithm>

// ---------------- problem constants ----------------
#define BATCH 32

static constexpr float SC1f = 0.03872983346207417f;   // 1/sqrt(2*30*1*10^4/30^2)
static constexpr float SC2f = 0.06324555320336759f;   // 1/sqrt(250)

// table layout (float offsets inside the table blob)
#define OFF_D1W 0
#define N_D1W (10*60*19)
#define OFF_C1  (OFF_D1W + N_D1W)      // [10][20][19][19]
#define N_C1  (10*20*19*19)
#define OFF_D2W (OFF_C1 + N_C1)        // [5][20][9][9]
#define N_D2W (5*20*81)
#define OFF_DH2 (OFF_D2W + N_D2W)      // [5][9][9]
#define N_DH2 (5*81)
#define OFF_DI2 (OFF_DH2 + N_DH2)      // [5][10][9][9]
#define N_DI2 (5*10*81)
#define OFF_WO  (OFF_DI2 + N_DI2)      // [10]
#define TBL_N   (OFF_WO + 10)

#define Z2HALF ((size_t)165*32*200)
#define NPART 5

__constant__ int d_RNI[9] = {9,16,21,24,25,24,21,16,9};
__constant__ int d_RS [9] = {0,9,25,46,70,95,119,140,156};

__device__ __forceinline__ float2 cmulf(float2 a, float2 b){
  return make_float2(a.x*b.x - a.y*b.y, a.x*b.y + a.y*b.x);
}

// ---------------- K_front v2 ----------------
// kf1 one-thread-per-(o,mi); incremental wrapped DFT indices everywhere.
//  blocks 0..7    : kf1  (1900 threads)
//  blocks 8..86   : kf2  (20000 threads)
//  blocks 87..229 : xf1  (36480 threads)
__global__ void k_front(const float* __restrict__ k1, const float* __restrict__ k2,
                        const float* __restrict__ x,
                        float2* __restrict__ kf1, float2* __restrict__ kf2,
                        float2* __restrict__ xf1){
  __shared__ float c60[60], s60[60], c20[20], s20[20];
  int t = threadIdx.x;
  if (t < 60){ float a = 6.283185307179586f * t / 60.f; c60[t]=cosf(a); s60[t]=sinf(a); }
  if (t < 20){ float a = 6.283185307179586f * t / 20.f; c20[t]=cosf(a); s20[t]=sinf(a); }
  __syncthreads();
  int bid = blockIdx.x;
  if (bid < 8){
    int gid = bid*256 + t;
    if (gid >= 1900) return;
    int o = gid/19, mi = gid%19;
    int m = mi-9;
    int step = m + 60; if (step >= 60) step -= 60;
    int idx = 0;
    float ax=0.f, ay=0.f;
    const float* kr = k1 + o*60;
    for (int j=0;j<60;j++){
      float kv = kr[j];
      ax += kv*c60[idx]; ay -= kv*s60[idx];
      idx += step; if (idx >= 60) idx -= 60;
    }
    kf1[mi*100+o] = make_float2(ax*SC1f, ay*SC1f);
  } else if (bid < 87){
    int gid = (bid-8)*256 + t;
    if (gid >= 20000) return;
    int i = gid/200, o = gid%200;
    float kv[20];
    #pragma unroll
    for (int p=0;p<20;p++) kv[p] = k2[(i*200+o)*20+p];
    #pragma unroll
    for (int mi=0; mi<9; mi++){
      int m = mi-4;
      int step = m + 20; if (step >= 20) step -= 20;
      int idx = 0;
      float ax=0.f, ay=0.f;
      #pragma unroll
      for (int p=0;p<20;p++){
        ax += kv[p]*c20[idx]; ay -= kv[p]*s20[idx];
        idx += step; if (idx >= 20) idx -= 20;
      }
      kf2[(size_t)(mi*100+i)*200+o] = make_float2(ax*SC2f, ay*SC2f);
    }
  } else {
    int gid = (bid-87)*256 + t;
    if (gid >= 19*32*60) return;
    int z = gid%60, b = (gid/60)%32, mi = gid/1920;
    int m = mi-9;
    int step = m + 60; if (step >= 60) step -= 60;
    int idx = 0;
    const float* xr = x + (b*60 + z)*60;
    float ax=0.f, ay=0.f;
    for (int j=0;j<60;j++){
      float xv = xr[j];
      ax += xv*c60[idx]; ay -= xv*s60[idx];
      idx += step; if (idx >= 60) idx -= 60;
    }
    xf1[(mi*32+b)*60+z] = make_float2(ax, ay);
  }
}

// ---------------- K3: fused xh1 + Q + P. Block per (b,z) ----------------
// k_xhat1 fused: the 190 xh1 values for this b recomputed per block (20x
// redundant across z, trivial; xf1 L2-resident) into 1.5KB LDS.
__launch_bounds__(256)
__global__ void k_QP(const float* __restrict__ tbl, const float2* __restrict__ xf1,
                     float2* __restrict__ P){
  __shared__ float2 xh1s[190];      // [l*19+mi]
  __shared__ float2 Qs[361];
  __shared__ float c20[20], s20[20];
  int t = threadIdx.x;
  if (t < 20){ float a = 6.283185307179586f * t / 20.f; c20[t]=cosf(a); s20[t]=sinf(a); }
  int bz = blockIdx.x;              // b*20+z
  int z = bz % 20, b = bz / 20;
  // stage 0: xh1[l][mi] for this b
  if (t < 190){
    int l = t/19, mi = t%19;
    const float* d1w = tbl + OFF_D1W;
    const float2* xr = xf1 + (size_t)(mi*32+b)*60;
    float ax=0.f, ay=0.f;
    for (int zz=0; zz<60; zz++){
      float w = d1w[(l*60+zz)*19+mi];
      float2 v = xr[zz];
      ax += w*v.x; ay += w*v.y;
    }
    xh1s[t] = make_float2(ax, ay);
  }
  __syncthreads();
  const float* C1 = tbl + OFF_C1;
  for (int e=t; e<361; e+=256){
    int mi = e/19;
    float ax=0.f, ay=0.f;
    #pragma unroll
    for (int l=0;l<10;l++){
      float c = C1[(l*20+z)*361 + e];
      float2 xv = xh1s[l*19+mi];            // LDS broadcast across the 19 ni
      ax += c*xv.x; ay += c*xv.y;
    }
    Qs[e] = make_float2(ax, ay);
  }
  __syncthreads();
  if (t < 200){
    int j1 = t%20, n = t/20;
    float px=0.f, py=0.f;
    int idx = (11*j1)%20;      // (-9*j1) mod 20
    int step = j1;
    #pragma unroll
    for (int mi=0;mi<19;mi++){
      float c=c20[idx], s=s20[idx];
      float2 v = Qs[mi*19 + n+9];           // same addr for 20 threads: broadcast
      px += c*v.x - s*v.y;
      py += c*v.y + s*v.x;
      idx += step; if (idx >= 20) idx -= 20;
    }
    P[(size_t)bz*200 + t] = make_float2(px, py);
  }
}

// ---------------- K4: fused layer-1 synth + ReLU + layer-2 analysis + xh2 ----------------
// v8 (kept): xh2 TRANSPOSED [widx][lmk] — verified: WRITE_SIZE 40.5->10.2MB
// (= logical), k_l1 55.5->52.3us. R11's total regression was the CONSUMER
// (k_Xp lost lane coalescing), fixed in k_Xp v3 below via LDS staging.
__launch_bounds__(256,2)
__global__ void k_l1(const float* __restrict__ tbl,
                     const float2* __restrict__ P, const float2* __restrict__ kf1,
                     const float* __restrict__ b1, float2* __restrict__ xh2){
  int o = blockIdx.x % 100, b = blockIdx.x / 100;

  __shared__ __align__(16) float2 tw9[10][10];
  __shared__ __align__(16) float2 tw5[5][10];
  __shared__ __align__(16) float  reA[4][20][12];
  __shared__ __align__(16) float  roA[4][20][12];
  __shared__ __align__(16) float2 AeA[4][5][10];
  __shared__ __align__(16) float2 AoA[4][5][10];
  __shared__ __align__(16) float2 xs[20][46];   // slab tile, padded rows

  int t = threadIdx.x, w = t>>6, lane = t&63;
  const float a1 = 0.3141592653589793f; // 2*pi/20

  for (int e=t; e<140; e+=256){
    if (e < 90){
      int j2=e/9, n=e%9+1;
      int idx=(n*j2)%20;
      float ang = a1*idx;
      tw9[j2][n-1] = make_float2(2.f*cosf(ang), -2.f*sinf(ang));
    } else {
      int q=e-90; int k=q/10, j=q%10;
      int idx=(k*j)%20;
      float ang = a1*idx;
      tw5[k][j] = make_float2(cosf(ang), -sinf(ang));
    }
  }

  float2 kc[10];
  #pragma unroll
  for (int n=0;n<10;n++){ float2 k = kf1[(n+9)*100+o]; kc[n]=make_float2(k.x,-k.y); }
  float b1v = b1[o];

  int j1 = lane%20, jg = lane/20;

  __syncthreads();

  float2 twB[10];
  {
    const float2* tb = &tw5[lane%5][0];
    #pragma unroll
    for (int j=0;j<10;j++) twB[j] = tb[j];
  }

  const float2* pz0 = P + (size_t)(b*20)*200;

  for (int zz=0; zz<5; zz++){
    int z = w*5 + zz;
    const float2* pz = pz0 + (size_t)z*200;
    float2 V[10];
    #pragma unroll
    for (int n=0;n<10;n++){
      float2 p = pz[n*20 + j1];
      V[n] = make_float2(p.x*kc[n].x - p.y*kc[n].y, p.x*kc[n].y + p.y*kc[n].x);
    }

    #pragma unroll
    for (int tt=0; tt<4; tt++){
      int j2 = jg + 3*tt;
      if (jg < 3 && j2 < 10){
        const float4* tq = (const float4*)&tw9[j2][0];
        float4 t0=tq[0], t1=tq[1], t2=tq[2], t3=tq[3];
        float2 t4=((const float2*)tq)[8];
        float o0=0.f, o1=0.f, e0=0.f, e1=0.f;
        o0 += V[1].x*t0.x + V[1].y*t0.y;
        e0 += V[2].x*t0.z + V[2].y*t0.w;
        o1 += V[3].x*t1.x + V[3].y*t1.y;
        e1 += V[4].x*t1.z + V[4].y*t1.w;
        o0 += V[5].x*t2.x + V[5].y*t2.y;
        e0 += V[6].x*t2.z + V[6].y*t2.w;
        o1 += V[7].x*t3.x + V[7].y*t3.y;
        e1 += V[8].x*t3.z + V[8].y*t3.w;
        o0 += V[9].x*t4.x + V[9].y*t4.y;
        float base = b1v + V[0].x;
        float e_ = e0+e1, o_ = o0+o1;
        float r0 = fmaxf(base + e_ + o_, 0.f);
        float r1 = fmaxf(base + e_ - o_, 0.f);
        reA[w][j1][j2] = r0 + r1;
        roA[w][j1][j2] = r0 - r1;
      }
    }

    if (lane < 50){
      int N = lane%5, j1p = lane/5;
      const float* rb = (N&1) ? &roA[w][0][0] : &reA[w][0][0];
      const float4* q0 = (const float4*)(rb + j1p*12);
      const float4* q1 = (const float4*)(rb + (j1p+10)*12);
      float4 x0=q0[0], x1=q0[1]; float2 x2=((const float2*)q0)[4];
      float4 y0=q1[0], y1=q1[1]; float2 y2=((const float2*)q1)[4];
      float r0v[10] = {x0.x,x0.y,x0.z,x0.w,x1.x,x1.y,x1.z,x1.w,x2.x,x2.y};
      float r1v[10] = {y0.x,y0.y,y0.z,y0.w,y1.x,y1.y,y1.z,y1.w,y2.x,y2.y};
      float ax0=0.f, ay0=0.f, ax1=0.f, ay1=0.f;
      #pragma unroll
      for (int j=0;j<10;j++){
        ax0 += r0v[j]*twB[j].x; ay0 += r0v[j]*twB[j].y;
        ax1 += r1v[j]*twB[j].x; ay1 += r1v[j]*twB[j].y;
      }
      AeA[w][N][j1p] = make_float2(ax0+ax1, ay0+ay1);
      AoA[w][N][j1p] = make_float2(ax0-ax1, ay0-ay1);
    }

    if (lane < 45){
      int M = lane/9, Ni = lane%9, Nv = Ni-4;
      int sidx = (Nv>=0)? Nv : -Nv;
      float ysgn = (Nv>=0)? 1.f : -1.f;
      const float4* Ab4 = (const float4*)((M&1) ? &AoA[w][sidx][0] : &AeA[w][sidx][0]);
      const float4* tC4 = (const float4*)&tw5[M][0];
      float ox0=0.f, ox1=0.f, oy0=0.f, oy1=0.f;
      #pragma unroll
      for (int q=0;q<5;q++){
        float4 Aq = Ab4[q];
        float4 Tq = tC4[q];
        float Ay0 = ysgn*Aq.y, Ay1 = ysgn*Aq.w;
        ox0 += Tq.x*Aq.x - Tq.y*Ay0;
        oy0 += Tq.x*Ay0 + Tq.y*Aq.x;
        ox1 += Tq.z*Aq.z - Tq.w*Ay1;
        oy1 += Tq.z*Ay1 + Tq.w*Aq.z;
      }
      xs[z][lane] = make_float2(ox0+ox1, oy0+oy1);   // LDS, not global
    }
  }

  // ---- fused xh2 accumulation: TRANSPOSED write xh2[b*100+o][lmk] ----
  __syncthreads();
  const float* d2w = tbl + OFF_D2W;
  float2* xrow = xh2 + (size_t)(b*100 + o)*405;
  for (int e=t; e<405; e+=256){
    int l = e/81, mk = e%81;
    int mi = mk/9, ki = mk%9;
    int sidx; float sgn;
    if (mi>=4){ sidx=(mi-4)*9+ki; sgn=1.f; }
    else      { sidx=(4-mi)*9+(8-ki); sgn=-1.f; }
    float ax=0.f, ay=0.f;
    #pragma unroll 4
    for (int z=0;z<20;z++){
      float wv = d2w[(l*20+z)*81+mk];
      float2 v = xs[z][sidx];
      ax += wv*v.x; ay += wv*sgn*v.y;
    }
    xrow[e] = make_float2(ax, ay);   // contiguous 3240B per block
  }
}

// ---------------- K6 v3: A rows via LDS-staged transposed xh2 ----------------
// R11's direct per-lane row walk lost coalescing (3240B lane stride, est +17us).
// v3: block = (ig, b); the 4 rows i0..i0+3 of transposed xh2 are CONTIGUOUS
// in memory (4*405 float2 = 12.96KB flat run) -> staged to LDS with perfectly
// coalesced loads; 660 outputs (165 g x 4 ii) computed from LDS; Am writes in
// 4-consecutive-i runs. Grid 25x32 = 800 blocks.
__launch_bounds__(256)
__global__ void k_Xp(const float* __restrict__ tbl, const float2* __restrict__ xh2,
                     float2* __restrict__ Am){
  __shared__ float2 xsh[4*405];
  int ig = blockIdx.x, b = blockIdx.y;
  int i0 = ig*4;
  int t = threadIdx.x;
  const float2* src = xh2 + (size_t)(b*100 + i0)*405;
  for (int e=t; e<1620; e+=256) xsh[e] = src[e];   // flat contiguous copy
  __syncthreads();
  const float* dh2 = tbl + OFF_DH2;
  for (int e=t; e<660; e+=256){
    int g = e>>2, ii = e&3;
    int ni = 0;
    while (ni < 8 && g >= d_RS[ni] + d_RNI[ni]) ni++;
    int r = g - d_RS[ni];
    int a = ni-4; if (a<0) a=-a;
    int l=a, rr=r;
    while (rr >= 2*l+1){ rr -= 2*l+1; l++; }
    int m = rr - l;
    const float* wrow = dh2 + l*81 + ni*9 + (4-l);
    const float2* vrow = &xsh[ii*405 + l*81 + (m+4)*9 + (4-l)];
    float ax=0.f, ay=0.f;
    for (int ki=0; ki<2*l+1; ki++){
      float wv = wrow[ki];
      float2 v = vrow[ki];
      ax += wv*v.x; ay += wv*v.y;
    }
    Am[(size_t)(g*32 + b)*100 + i0 + ii] = make_float2(ax, ay);
  }
}

// ---------------- K7: complex GEMM v3 (measured best) ----------------
// col-tiles of 40 (5x40=200 exact); K-split x5 (K=20/block, single stage +
// single barrier); 2125 active blocks. R8 showed block-count beats traffic.
__launch_bounds__(256)
__global__ void k_gemm(const float2* __restrict__ Am, const float2* __restrict__ kf2,
                       float2* __restrict__ z2p){
  int zi = blockIdx.z;            // 0..44 = ni*5 + ks
  int ni = zi/5, ks = zi%5;
  int rows = d_RNI[ni]*32;
  int r0 = blockIdx.x*64;
  if (r0 >= rows) return;
  int c0 = blockIdx.y*40;
  const float2* Ab = Am + (size_t)d_RS[ni]*32*100;
  const float2* Bb = kf2 + (size_t)ni*20000 + (size_t)ks*20*200;
  float2* Cb = z2p + (size_t)ks*Z2HALF + (size_t)d_RS[ni]*32*200;
  __shared__ float2 Asx[64*21];   // [m][k], pad 21
  __shared__ float2 Bsx[20*40];   // [k][n]
  int t = threadIdx.x;
  #pragma unroll
  for (int e=t; e<1280; e+=256){
    int m=e/20, k=e%20;
    float2 v=make_float2(0.f,0.f);
    if (r0+m<rows) v=Ab[(size_t)(r0+m)*100 + ks*20 + k];
    Asx[m*21+k]=v;
  }
  for (int e=t; e<800; e+=256){
    int k=e/40, n=e%40;
    float2 v=Bb[(size_t)k*200 + c0+n];
    v.y=-v.y;
    Bsx[k*40+n]=v;
  }
  __syncthreads();
  int tx = t%8, ty = t/8;   // cols c0+tx*5.., rows r0+ty*2..
  float2 acc[2][5];
  #pragma unroll
  for (int i=0;i<2;i++)
    #pragma unroll
    for (int j=0;j<5;j++) acc[i][j]=make_float2(0.f,0.f);
  #pragma unroll 4
  for (int k=0;k<20;k++){
    float2 a0=Asx[(ty*2)*21+k], a1=Asx[(ty*2+1)*21+k];
    float2 bv[5];
    #pragma unroll
    for (int j=0;j<5;j++) bv[j]=Bsx[k*40+tx*5+j];
    #pragma unroll
    for (int j=0;j<5;j++){
      acc[0][j].x += a0.x*bv[j].x - a0.y*bv[j].y;
      acc[0][j].y += a0.x*bv[j].y + a0.y*bv[j].x;
      acc[1][j].x += a1.x*bv[j].x - a1.y*bv[j].y;
      acc[1][j].y += a1.x*bv[j].y + a1.y*bv[j].x;
    }
  }
  #pragma unroll
  for (int i=0;i<2;i++){
    int row=r0+ty*2+i;
    if (row<rows){
      #pragma unroll
      for (int j=0;j<5;j++) Cb[(size_t)row*200 + c0+tx*5+j]=acc[i][j];
    }
  }
}

// ---------------- K8: fused layer-2 synthesis + ReLU + quadrature pooling ----------------
// Block = (b, o-group-of-8), 512 threads, 8 waves; wave w owns o = og*8+w and
// all 10 z. Load sums the 5 partials reading 8 consecutive o per slot = one
// aligned 64B line, each line touched once across the grid.
__launch_bounds__(512)
__global__ void k_l2(const float* __restrict__ tbl, const float2* __restrict__ z2p,
                     const float* __restrict__ b2, float* __restrict__ fv){
  int b = blockIdx.x / 25, og = blockIdx.x % 25;
  __shared__ float2 zlh8[8][225];  // [o_l][slot]
  __shared__ float  c10s[10], s10s[10];
  __shared__ float2 Gw[8][45];
  __shared__ float2 Fw[8][50];
  int t = threadIdx.x, w = t>>6, lane = t&63;
  if (t < 10){ float a = 0.6283185307179586f * t; c10s[t]=cosf(a); s10s[t]=sinf(a); }
  int o0 = og*8;
  for (int e=t;e<1800;e+=512){
    int slot=e>>3, o_l=e&7;
    int l=slot/45, rm=slot%45, m=rm/9, nii=rm%9;
    int n=nii-4, an = n<0?-n:n;
    float2 v=make_float2(0.f,0.f);
    if (l >= m && l >= an){
      size_t idx = (size_t)((d_RS[nii] + (l*l - an*an + m + l))*32+b)*200 + o0 + o_l;
      #pragma unroll
      for (int p=0;p<NPART;p++){
        float2 vp = z2p[idx + (size_t)p*Z2HALF];
        v.x += vp.x; v.y += vp.y;
      }
    }
    zlh8[o_l][slot]=v;
  }
  __syncthreads();
  const float* di2 = tbl + OFF_DI2;
  const float* wo  = tbl + OFF_WO;
  int o = o0 + w;
  float b2v = b2[o];
  float accv = 0.f;
  for (int z=0; z<10; z++){
    if (lane < 45){
      int m=lane/9, nii=lane%9;
      float gx=0.f, gy=0.f;
      #pragma unroll
      for (int l=0;l<5;l++){
        float wv = di2[(l*10+z)*81 + (m+4)*9 + nii];
        float2 v = zlh8[w][(l*5+m)*9+nii];
        gx += wv*v.x; gy += wv*v.y;
      }
      Gw[w][lane]=make_float2(gx,gy);
    }
    if (lane < 50){
      int m=lane/10, j2=lane%10;
      if (m==0){
        float f0 = Gw[w][4].x;
        #pragma unroll
        for (int n=1;n<=4;n++){
          int idx=(n*j2)%10;
          float2 g=Gw[w][4+n];
          f0 += 2.f*(c10s[idx]*g.x - s10s[idx]*g.y);
        }
        Fw[w][lane]=make_float2(f0, 0.f);
      } else {
        float fx=0.f, fy=0.f;
        #pragma unroll
        for (int nii=0;nii<9;nii++){
          int n=nii-4;
          int idx=((n*j2)%10+10)%10;
          float2 g=Gw[w][m*9+nii];
          fx += c10s[idx]*g.x - s10s[idx]*g.y;
          fy += s10s[idx]*g.x + c10s[idx]*g.y;
        }
        Fw[w][lane]=make_float2(fx,fy);
      }
    }
    float wz = wo[z];
    {
      int j1=lane/10, j2=lane%10;
      float v = b2v + Fw[w][j2].x;
      #pragma unroll
      for (int m=1;m<=4;m++){
        int idx=(m*j1)%10;
        float2 f=Fw[w][m*10+j2];
        v += 2.f*(c10s[idx]*f.x - s10s[idx]*f.y);
      }
      accv += wz*fmaxf(v,0.f);
    }
    if (lane < 36){
      int e=lane+64, j1=e/10, j2=e%10;
      float v = b2v + Fw[w][j2].x;
      #pragma unroll
      for (int m=1;m<=4;m++){
        int idx=(m*j1)%10;
        float2 f=Fw[w][m*10+j2];
        v += 2.f*(c10s[idx]*f.x - s10s[idx]*f.y);
      }
      accv += wz*fmaxf(v,0.f);
    }
  }
  #pragma unroll
  for (int s=32;s>0;s>>=1) accv += __shfl_down(accv, s);
  if (lane==0) fv[b*200+o]=accv;
}

// ---------------- K9: out[b][c] = bl[c] + sum_o W[c][o] fv[b][o]; one block per b ----------------
__global__ void k_out(const float* __restrict__ fv, const float* __restrict__ W,
                      const float* __restrict__ bl, float* __restrict__ out){
  int b = blockIdx.x, lane = threadIdx.x;
  float acc[10];
  #pragma unroll
  for (int c=0;c<10;c++) acc[c]=0.f;
  #pragma unroll
  for (int k=0;k<4;k++){
    int o = lane + 64*k;
    if (o < 200){
      float fvx = fv[b*200+o];
      #pragma unroll
      for (int c=0;c<10;c++) acc[c] += W[c*200+o]*fvx;
    }
  }
  #pragma unroll
  for (int c=0;c<10;c++){
    float a = acc[c];
    #pragma unroll
    for (int s=32;s>0;s>>=1) a += __shfl_down(a, s);
    if (lane==0) out[b*10+c] = a + bl[c];
  }
}

// ======================= host-side constant tables =======================
namespace {

double dfact_[40];
void init_fact(){ dfact_[0]=1.0; for (int i=1;i<40;i++) dfact_[i]=dfact_[i-1]*i; }

double wigd(int l, double beta, int m, int n){
  double cb=std::cos(beta*0.5), sb=std::sin(beta*0.5);
  double pref=std::sqrt(dfact_[l+m]*dfact_[l-m]*dfact_[l+n]*dfact_[l-n]);
  int s0=std::max(0,n-m), s1=std::min(l+n,l-m);
  double acc=0.0;
  for (int s=s0;s<=s1;s++){
    double den=dfact_[l+n-s]*dfact_[s]*dfact_[m-n+s]*dfact_[l-m-s];
    double sg=((m-n+s)&1)?-1.0:1.0;
    acc+=sg/den*std::pow(cb,(double)(2*l+n-m-2*s))*std::pow(sb,(double)(m-n+2*s));
  }
  return pref*acc;
}

void quadw(int b, double* betas, double* w){
  int n=2*b;
  for (int j=0;j<n;j++){
    betas[j]=M_PI*(2*j+1)/(4.0*b);
    double s=0.0;
    for (int k=1;k<2*b;k+=2) s+=std::sin(k*betas[j])/k;
    w[j]=2.0/b*std::sin(betas[j])*s;
  }
}

float* g_tbl_host = nullptr;

void build_tables(){
  init_fact();
  double bin[60], win[60], bl1[20], wl1[20], bo10[10], wo10[10];
  quadw(30,bin,win); quadw(10,bl1,wl1); quadw(5,bo10,wo10);
  float* T = g_tbl_host;
  memset(T, 0, TBL_N*sizeof(float));
  for (int l=0;l<10;l++) for (int z=0;z<60;z++) for (int mi=0;mi<19;mi++){
    int m=mi-9; if (m<-l||m>l) continue;
    T[OFF_D1W+(l*60+z)*19+mi]=(float)(win[z]*wigd(l,bin[z],m,0));
  }
  for (int l=0;l<10;l++) for (int z=0;z<20;z++) for (int mi=0;mi<19;mi++) for (int ni=0;ni<19;ni++){
    int m=mi-9, n=ni-9; if (m<-l||m>l||n<-l||n>l) continue;
    T[OFF_C1+(l*20+z)*361+mi*19+ni]=(float)((2*l+1)*wigd(l,bl1[z],m,n)*wigd(l,M_PI/2,n,0));
  }
  for (int l=0;l<5;l++) for (int z=0;z<20;z++) for (int mi=0;mi<9;mi++) for (int ki=0;ki<9;ki++){
    int m=mi-4, k=ki-4; if (m<-l||m>l||k<-l||k>l) continue;
    T[OFF_D2W+(l*20+z)*81+mi*9+ki]=(float)(wl1[z]*wigd(l,bl1[z],m,k));
  }
  for (int l=0;l<5;l++) for (int ni=0;ni<9;ni++) for (int ki=0;ki<9;ki++){
    int n=ni-4, k=ki-4; if (n<-l||n>l||k<-l||k>l) continue;
    T[OFF_DH2+l*81+ni*9+ki]=(float)wigd(l,M_PI/2,n,k);
  }
  for (int l=0;l<5;l++) for (int z=0;z<10;z++) for (int mi=0;mi<9;mi++) for (int ni=0;ni<9;ni++){
    int m=mi-4, n=ni-4; if (m<-l||m>l||n<-l||n>l) continue;
    T[OFF_DI2+(l*10+z)*81+mi*9+ni]=(float)((2*l+1)*wigd(l,bo10[z],m,n));
  }
  for (int z=0;z<10;z++) T[OFF_WO+z]=(float)wo10[z];
}

struct GInit {
  GInit(){
    if (hipHostMalloc((void**)&g_tbl_host, TBL_N*sizeof(float)) != hipSuccess || !g_tbl_host){
      g_tbl_host = (float*)malloc(TBL_N*sizeof(float));
    }
    build_tables();
  }
};
GInit g_init_;

} // namespace

extern "C" void kernel_launch(void* const* d_in, const int* in_sizes, int n_in,
                              void* d_out, int out_size, void* d_ws, size_t ws_size,
                              hipStream_t stream) {
  const float* x  = (const float*)d_in[0];
  const float* k1 = (const float*)d_in[1];
  const float* b1 = (const float*)d_in[2];
  const float* k2 = (const float*)d_in[3];
  const float* b2 = (const float*)d_in[4];
  const float* W  = (const float*)d_in[5];
  const float* bl = (const float*)d_in[6];
  float* out = (float*)d_out;

  size_t off = 0;
  auto carve = [&](size_t bytes)->void*{
    void* p = (char*)d_ws + off;
    off += (bytes + 255) & ~(size_t)255;
    return p;
  };
  float*  t_tbl = (float*) carve((size_t)TBL_N*4);
  float2* kf1   = (float2*)carve((size_t)19*100*8);
  float2* kf2   = (float2*)carve((size_t)9*100*200*8);
  float2* xf1   = (float2*)carve((size_t)19*32*60*8);
  float2* Pb    = (float2*)carve((size_t)32*20*200*8);
  float2* xh2   = (float2*)carve((size_t)3200*405*8);   // transposed [widx][lmk]
  float2* Am    = (float2*)carve((size_t)165*32*100*8);
  float2* z2p   = (float2*)carve((size_t)NPART*Z2HALF*8); // five K-partials
  float*  fv    = (float*) carve((size_t)6400*4);
  (void)ws_size; (void)in_sizes; (void)n_in; (void)out_size;

  hipMemcpyAsync(t_tbl, g_tbl_host, (size_t)TBL_N*4, hipMemcpyHostToDevice, stream);

  k_front<<<230, 256, 0, stream>>>(k1, k2, x, kf1, kf2, xf1);
  k_QP   <<<640, 256, 0, stream>>>(t_tbl, xf1, Pb);
  k_l1   <<<3200, 256, 0, stream>>>(t_tbl, Pb, kf1, b1, xh2);
  k_Xp   <<<dim3(25, 32), 256, 0, stream>>>(t_tbl, xh2, Am);
  k_gemm <<<dim3(13, 5, 45), 256, 0, stream>>>(Am, kf2, z2p);
  k_l2   <<<800, 512, 0, stream>>>(t_tbl, z2p, b2, fv);
  k_out  <<<32, 64, 0, stream>>>(fv, W, bl, out);
}